// Round 2
// baseline (1036.356 us; speedup 1.0000x reference)
//
#include <hip/hip_runtime.h>
#include <hip/hip_cooperative_groups.h>

namespace cg = cooperative_groups;

typedef __attribute__((ext_vector_type(8))) short short8;
typedef __attribute__((ext_vector_type(4))) float f32x4;

__device__ __forceinline__ unsigned short f2bf(float f) {
    union { float f; unsigned int i; } v; v.f = f;
    unsigned int x = v.i;
    return (unsigned short)((x + 0x7FFFu + ((x >> 16) & 1u)) >> 16); // RNE, finite inputs
}
__device__ __forceinline__ f32x4 mfma16(short8 a, short8 b, f32x4 c) {
    return __builtin_amdgcn_mfma_f32_16x16x32_bf16(a, b, c, 0, 0, 0);
}

#define NBLK 1024

// ---------------------------------------------------------------------------
// MEGA: all 4 phases in one cooperative kernel; grid.sync() between phases.
// Phase bodies identical to the proven 4-kernel pipeline (180.4 us); this
// round isolates inter-kernel overhead (launch + drain-to-idle between 4
// dependent dispatches) which the arithmetic says is ~140 us of the 180.
// Grid 1024 x 256 = 4 blocks/CU exactly; launch_bounds(256,4) caps VGPR at
// 128 so cooperative co-residency holds; LDS union 16.4 KB -> 65.8 KB/CU.
// ---------------------------------------------------------------------------
__global__ void __launch_bounds__(256, 4)
mega_kernel(const float* __restrict__ x,
            const float* __restrict__ Wq, const float* __restrict__ Wk,
            const float* __restrict__ Wv,
            const float* __restrict__ bq, const float* __restrict__ bk,
            const float* __restrict__ bv,
            float* __restrict__ out,
            unsigned short* __restrict__ Wb,
            unsigned short* __restrict__ xavg,
            unsigned short* __restrict__ xsum,
            unsigned short* __restrict__ QK,
            unsigned short* __restrict__ VsT,
            unsigned short* __restrict__ Amat)
{
    __shared__ union {
        float part2[1024];
        float S[16][257];
        float osT[64][17];
    } u;
    const int t = threadIdx.x;
    cg::grid_group grid = cg::this_grid();

    // ---------------- Phase A: plane reductions + weight convert ----------
    for (int blk = (int)blockIdx.x; blk < 4480; blk += NBLK) {
        if (blk >= 4096) {                  // weight conversion (no LDS)
            const int f = (blk - 4096) * 512 + t;
            const int m = f >> 16;
            const int o = f & 65535;
            const float4* s4 = (const float4*)((m == 0) ? Wq : (m == 1) ? Wk : Wv);
            float4 a = s4[o];
            float4 b = s4[o + 256];
            ushort4* d4 = (ushort4*)(Wb + (size_t)m * 262144);
            d4[o]       = make_ushort4(f2bf(a.x), f2bf(a.y), f2bf(a.z), f2bf(a.w));
            d4[o + 256] = make_ushort4(f2bf(b.x), f2bf(b.y), f2bf(b.z), f2bf(b.w));
        } else {                            // one (b,c) plane
            const int b = blk >> 9;
            const int c = blk & 511;
            const float4* x4 = (const float4*)(x + (size_t)blk * 4096);
            float4 f0 = x4[t], f1 = x4[t + 256], f2 = x4[t + 512], f3 = x4[t + 768];
            u.part2[t]       = f0.x + f0.y + f0.z + f0.w;
            u.part2[t + 256] = f1.x + f1.y + f1.z + f1.w;
            u.part2[t + 512] = f2.x + f2.y + f2.z + f2.w;
            u.part2[t + 768] = f3.x + f3.y + f3.z + f3.w;
            __syncthreads();
            {
                const int base = 16 * (t >> 2) + 4 * (t & 3);
                float4 q = *(const float4*)&u.part2[base];
                xsum[((size_t)b * 256 + t) * 512 + c] = f2bf(q.x + q.y + q.z + q.w);
            }
            {
                const int bh = t >> 4, bw = t & 15;
                float m2 = (u.part2[(bh * 4 + 0) * 16 + bw] + u.part2[(bh * 4 + 1) * 16 + bw] +
                            u.part2[(bh * 4 + 2) * 16 + bw] + u.part2[(bh * 4 + 3) * 16 + bw]) * 0.0625f;
                xavg[((size_t)b * 256 + t) * 512 + c] = f2bf(m2);
            }
            __syncthreads();                // part2 reused next grid-stride iter
        }
    }
    __threadfence();                        // agent-scope release (L2 wb) before barrier
    grid.sync();
    __threadfence();

    // ---------------- Phase B: QK and V projections ------------------------
    {
        const int lane = t & 63, quad = lane >> 4, r16 = lane & 15;
        const int w = t >> 6;
        for (int blk = (int)blockIdx.x; blk < 384; blk += NBLK) {
            if (blk < 256) {                // ---- QK projection ----
                const int wave = blk * 4 + w;
                const int mt2 = wave >> 4;
                const int nt4 = wave & 15;
                const unsigned short* xp0 = xavg + (size_t)(mt2 * 32 + r16) * 512 + quad * 8;
                const unsigned short* xp1 = xp0 + 16 * 512;
                const unsigned short* wp0 = Wb + (size_t)(nt4 * 64 + r16) * 512 + quad * 8;
                const unsigned short* wp1 = wp0 + 16 * 512;
                const unsigned short* wp2 = wp0 + 32 * 512;
                const unsigned short* wp3 = wp0 + 48 * 512;

                f32x4 a00 = {0,0,0,0}, a01 = a00, a02 = a00, a03 = a00;
                f32x4 a10 = a00, a11 = a00, a12 = a00, a13 = a00;
#pragma unroll 4
                for (int k = 0; k < 512; k += 32) {
                    short8 qa0 = *(const short8*)(xp0 + k);
                    short8 qa1 = *(const short8*)(xp1 + k);
                    short8 b0 = *(const short8*)(wp0 + k);
                    short8 b1 = *(const short8*)(wp1 + k);
                    short8 b2 = *(const short8*)(wp2 + k);
                    short8 b3 = *(const short8*)(wp3 + k);
                    a00 = mfma16(qa0, b0, a00); a01 = mfma16(qa0, b1, a01);
                    a02 = mfma16(qa0, b2, a02); a03 = mfma16(qa0, b3, a03);
                    a10 = mfma16(qa1, b0, a10); a11 = mfma16(qa1, b1, a11);
                    a12 = mfma16(qa1, b2, a12); a13 = mfma16(qa1, b3, a13);
                }
                const int row0 = mt2 * 32 + quad * 4;
                f32x4 accs0[4] = {a00, a01, a02, a03};
                f32x4 accs1[4] = {a10, a11, a12, a13};
#pragma unroll
                for (int j = 0; j < 4; ++j) {
                    const int c = nt4 * 64 + j * 16 + r16;
                    const float bias = (c < 512) ? bq[c] : bk[c - 512];
#pragma unroll
                    for (int r = 0; r < 4; ++r) {
                        QK[(size_t)(row0 + r) * 1024 + c]      = f2bf(accs0[j][r] + bias);
                        QK[(size_t)(row0 + 16 + r) * 1024 + c] = f2bf(accs1[j][r] + bias);
                    }
                }
            } else {                        // ---- V projection (transposed) ----
                const int vblk = blk - 256;
                const int b = vblk >> 4;
                const int wave = (vblk & 15) * 4 + w;
                const int mt2 = wave >> 3;
                const int nt4 = wave & 7;
                const unsigned short* xp0 = xsum + (size_t)b * 131072 + (size_t)(mt2 * 32 + r16) * 512 + quad * 8;
                const unsigned short* xp1 = xp0 + 16 * 512;
                const unsigned short* wp0 = Wb + 524288 + (size_t)(nt4 * 64 + r16) * 512 + quad * 8;
                const unsigned short* wp1 = wp0 + 16 * 512;
                const unsigned short* wp2 = wp0 + 32 * 512;
                const unsigned short* wp3 = wp0 + 48 * 512;

                f32x4 a00 = {0,0,0,0}, a01 = a00, a02 = a00, a03 = a00;
                f32x4 a10 = a00, a11 = a00, a12 = a00, a13 = a00;
#pragma unroll 4
                for (int k = 0; k < 512; k += 32) {
                    short8 qa0 = *(const short8*)(xp0 + k);
                    short8 qa1 = *(const short8*)(xp1 + k);
                    short8 b0 = *(const short8*)(wp0 + k);
                    short8 b1 = *(const short8*)(wp1 + k);
                    short8 b2 = *(const short8*)(wp2 + k);
                    short8 b3 = *(const short8*)(wp3 + k);
                    a00 = mfma16(qa0, b0, a00); a01 = mfma16(qa0, b1, a01);
                    a02 = mfma16(qa0, b2, a02); a03 = mfma16(qa0, b3, a03);
                    a10 = mfma16(qa1, b0, a10); a11 = mfma16(qa1, b1, a11);
                    a12 = mfma16(qa1, b2, a12); a13 = mfma16(qa1, b3, a13);
                }
                unsigned short* vb = VsT + (size_t)b * 131072;
                const int m0 = mt2 * 32 + quad * 4;
                f32x4 accs0[4] = {a00, a01, a02, a03};
                f32x4 accs1[4] = {a10, a11, a12, a13};
#pragma unroll
                for (int j = 0; j < 4; ++j) {
                    const int c = nt4 * 64 + j * 16 + r16;
                    const float bias = 16.f * bv[c];
#pragma unroll
                    for (int r = 0; r < 4; ++r) {
                        vb[(size_t)c * 256 + m0 + r]      = f2bf(accs0[j][r] + bias);
                        vb[(size_t)c * 256 + m0 + 16 + r] = f2bf(accs1[j][r] + bias);
                    }
                }
            }
        }
    }
    __threadfence();
    grid.sync();
    __threadfence();

    // ---------------- Phase C: scores + softmax ----------------------------
    for (int vb = (int)blockIdx.x; vb < 128; vb += NBLK) {
        const int b = vb >> 4, strip = vb & 15;
        const int w = t >> 6, lane = t & 63;
        const int quad = lane >> 4, r16 = lane & 15;
        {
            const unsigned short* qp = QK + (size_t)(b * 256 + strip * 16 + r16) * 1024 + quad * 8;
            const unsigned short* kp0 = QK + (size_t)(b * 256 + w * 64 + r16) * 1024 + 512 + quad * 8;
            const unsigned short* kp1 = kp0 + 16 * 1024;
            const unsigned short* kp2 = kp0 + 32 * 1024;
            const unsigned short* kp3 = kp0 + 48 * 1024;

            f32x4 a0 = {0,0,0,0}, a1 = a0, a2 = a0, a3 = a0;
#pragma unroll 4
            for (int k = 0; k < 512; k += 32) {
                short8 qa = *(const short8*)(qp + k);
                short8 b0 = *(const short8*)(kp0 + k);
                short8 b1 = *(const short8*)(kp1 + k);
                short8 b2 = *(const short8*)(kp2 + k);
                short8 b3 = *(const short8*)(kp3 + k);
                a0 = mfma16(qa, b0, a0); a1 = mfma16(qa, b1, a1);
                a2 = mfma16(qa, b2, a2); a3 = mfma16(qa, b3, a3);
            }
            f32x4 accs[4] = {a0, a1, a2, a3};
#pragma unroll
            for (int j = 0; j < 4; ++j) {
                const int col = w * 64 + j * 16 + r16;
#pragma unroll
                for (int r = 0; r < 4; ++r)
                    u.S[quad * 4 + r][col] = accs[j][r];
            }
        }
        __syncthreads();
        {
            const int r = t >> 4, idx = t & 15;
            float v[16];
            float mx = -3.4e38f;
#pragma unroll
            for (int j = 0; j < 16; ++j) {
                v[j] = u.S[r][idx * 16 + j] * 0.044194173824159216f;
                mx = fmaxf(mx, v[j]);
            }
            mx = fmaxf(mx, __shfl_xor(mx, 1));
            mx = fmaxf(mx, __shfl_xor(mx, 2));
            mx = fmaxf(mx, __shfl_xor(mx, 4));
            mx = fmaxf(mx, __shfl_xor(mx, 8));
            float sum = 0.f;
#pragma unroll
            for (int j = 0; j < 16; ++j) { v[j] = __expf(v[j] - mx); sum += v[j]; }
            sum += __shfl_xor(sum, 1);
            sum += __shfl_xor(sum, 2);
            sum += __shfl_xor(sum, 4);
            sum += __shfl_xor(sum, 8);
            const float inv = 1.f / sum;
            unsigned short* ap = Amat + (size_t)b * 65536 + (size_t)(strip * 16 + r) * 256 + idx * 16;
#pragma unroll
            for (int j = 0; j < 16; j += 4)
                *(ushort4*)(ap + j) = make_ushort4(f2bf(v[j] * inv), f2bf(v[j + 1] * inv),
                                                   f2bf(v[j + 2] * inv), f2bf(v[j + 3] * inv));
        }
        __syncthreads();                    // S reused if another strip (not at NBLK=1024, kept for safety)
    }
    __threadfence();
    grid.sync();
    __threadfence();

    // ---------------- Phase D: out = expand16(A @ Vsum) --------------------
    {
        const int vb = (int)blockIdx.x;     // exactly NBLK virtual blocks
        const int b = vb >> 7;
        const int bx = vb & 127;
        const int sh = bx >> 3;
        const int cq = bx & 7;
        const int w = t >> 6, lane = t & 63;
        const int quad = lane >> 4, r16 = lane & 15;
        {
            const unsigned short* ap = Amat + (size_t)b * 65536 + (size_t)(sh * 16 + r16) * 256 + quad * 8;
            const unsigned short* vp = VsT + (size_t)b * 131072 +
                                       (size_t)(cq * 64 + w * 16 + r16) * 256 + quad * 8;
            f32x4 acc = {0.f, 0.f, 0.f, 0.f};
#pragma unroll
            for (int k = 0; k < 256; k += 32) {
                short8 a0 = *(const short8*)(ap + k);
                short8 b0 = *(const short8*)(vp + k);
                acc = mfma16(a0, b0, acc);
            }
#pragma unroll
            for (int r = 0; r < 4; ++r)
                u.osT[w * 16 + r16][quad * 4 + r] = acc[r];
        }
        __syncthreads();
        {
            const int ch4 = t >> 6;
            const int j = t & 63;
            const int n = j >> 2;
            float* obase = out + (size_t)(b * 512 + cq * 64) * 4096 + sh * 256 + j * 4;
#pragma unroll
            for (int it = 0; it < 16; ++it) {
                const int ch = it * 4 + ch4;
                const float v = u.osT[ch][n];
                *(float4*)(obase + (size_t)ch * 4096) = make_float4(v, v, v, v);
            }
        }
    }
}

// ===========================================================================
// Fallback path: original 4-kernel pipeline (used only if cooperative launch
// is rejected by the runtime).
// ===========================================================================
__global__ void prep_kernel(const float* __restrict__ x,
                            const float* __restrict__ Wq,
                            const float* __restrict__ Wk,
                            const float* __restrict__ Wv,
                            unsigned short* __restrict__ xavg,
                            unsigned short* __restrict__ xsum,
                            unsigned short* __restrict__ Wb)
{
    const int blk = blockIdx.x;
    const int t = threadIdx.x;
    if (blk >= 4096) {
        const int f = (blk - 4096) * 512 + t;
        const int m = f >> 16;
        const int o = f & 65535;
        const float4* s4 = (const float4*)((m == 0) ? Wq : (m == 1) ? Wk : Wv);
        float4 a = s4[o];
        float4 b = s4[o + 256];
        ushort4* d4 = (ushort4*)(Wb + (size_t)m * 262144);
        d4[o]       = make_ushort4(f2bf(a.x), f2bf(a.y), f2bf(a.z), f2bf(a.w));
        d4[o + 256] = make_ushort4(f2bf(b.x), f2bf(b.y), f2bf(b.z), f2bf(b.w));
        return;
    }
    const int b = blk >> 9;
    const int c = blk & 511;

    const float4* x4 = (const float4*)(x + (size_t)blk * 4096);
    float4 f0 = x4[t], f1 = x4[t + 256], f2 = x4[t + 512], f3 = x4[t + 768];

    __shared__ float part2[1024];
    part2[t]       = f0.x + f0.y + f0.z + f0.w;
    part2[t + 256] = f1.x + f1.y + f1.z + f1.w;
    part2[t + 512] = f2.x + f2.y + f2.z + f2.w;
    part2[t + 768] = f3.x + f3.y + f3.z + f3.w;
    __syncthreads();
    {
        const int base = 16 * (t >> 2) + 4 * (t & 3);
        float4 q = *(const float4*)&part2[base];
        xsum[((size_t)b * 256 + t) * 512 + c] = f2bf(q.x + q.y + q.z + q.w);
    }
    {
        const int bh = t >> 4, bw = t & 15;
        float m = (part2[(bh * 4 + 0) * 16 + bw] + part2[(bh * 4 + 1) * 16 + bw] +
                   part2[(bh * 4 + 2) * 16 + bw] + part2[(bh * 4 + 3) * 16 + bw]) * 0.0625f;
        xavg[((size_t)b * 256 + t) * 512 + c] = f2bf(m);
    }
}

__global__ void __launch_bounds__(256, 2)
proj_gemm(const unsigned short* __restrict__ xavg,
          const unsigned short* __restrict__ xsum,
          const unsigned short* __restrict__ Wb,
          const float* __restrict__ bq,
          const float* __restrict__ bk,
          const float* __restrict__ bv,
          unsigned short* __restrict__ QK,
          unsigned short* __restrict__ VsT)
{
    const int blk = blockIdx.x;
    const int lane = threadIdx.x & 63, quad = lane >> 4, r16 = lane & 15;
    const int w = threadIdx.x >> 6;

    if (blk < 256) {
        const int wave = blk * 4 + w;
        const int mt2 = wave >> 4;
        const int nt4 = wave & 15;
        const unsigned short* xp0 = xavg + (size_t)(mt2 * 32 + r16) * 512 + quad * 8;
        const unsigned short* xp1 = xp0 + 16 * 512;
        const unsigned short* wp0 = Wb + (size_t)(nt4 * 64 + r16) * 512 + quad * 8;
        const unsigned short* wp1 = wp0 + 16 * 512;
        const unsigned short* wp2 = wp0 + 32 * 512;
        const unsigned short* wp3 = wp0 + 48 * 512;

        f32x4 a00 = {0,0,0,0}, a01 = a00, a02 = a00, a03 = a00;
        f32x4 a10 = a00, a11 = a00, a12 = a00, a13 = a00;
#pragma unroll 4
        for (int k = 0; k < 512; k += 32) {
            short8 qa0 = *(const short8*)(xp0 + k);
            short8 qa1 = *(const short8*)(xp1 + k);
            short8 b0 = *(const short8*)(wp0 + k);
            short8 b1 = *(const short8*)(wp1 + k);
            short8 b2 = *(const short8*)(wp2 + k);
            short8 b3 = *(const short8*)(wp3 + k);
            a00 = mfma16(qa0, b0, a00); a01 = mfma16(qa0, b1, a01);
            a02 = mfma16(qa0, b2, a02); a03 = mfma16(qa0, b3, a03);
            a10 = mfma16(qa1, b0, a10); a11 = mfma16(qa1, b1, a11);
            a12 = mfma16(qa1, b2, a12); a13 = mfma16(qa1, b3, a13);
        }
        const int row0 = mt2 * 32 + quad * 4;
        f32x4 accs0[4] = {a00, a01, a02, a03};
        f32x4 accs1[4] = {a10, a11, a12, a13};
#pragma unroll
        for (int j = 0; j < 4; ++j) {
            const int c = nt4 * 64 + j * 16 + r16;
            const float bias = (c < 512) ? bq[c] : bk[c - 512];
#pragma unroll
            for (int r = 0; r < 4; ++r) {
                QK[(size_t)(row0 + r) * 1024 + c]      = f2bf(accs0[j][r] + bias);
                QK[(size_t)(row0 + 16 + r) * 1024 + c] = f2bf(accs1[j][r] + bias);
            }
        }
    } else {
        const int vblk = blk - 256;
        const int b = vblk >> 4;
        const int wave = (vblk & 15) * 4 + w;
        const int mt2 = wave >> 3;
        const int nt4 = wave & 7;
        const unsigned short* xp0 = xsum + (size_t)b * 131072 + (size_t)(mt2 * 32 + r16) * 512 + quad * 8;
        const unsigned short* xp1 = xp0 + 16 * 512;
        const unsigned short* wp0 = Wb + 524288 + (size_t)(nt4 * 64 + r16) * 512 + quad * 8;
        const unsigned short* wp1 = wp0 + 16 * 512;
        const unsigned short* wp2 = wp0 + 32 * 512;
        const unsigned short* wp3 = wp0 + 48 * 512;

        f32x4 a00 = {0,0,0,0}, a01 = a00, a02 = a00, a03 = a00;
        f32x4 a10 = a00, a11 = a00, a12 = a00, a13 = a00;
#pragma unroll 4
        for (int k = 0; k < 512; k += 32) {
            short8 qa0 = *(const short8*)(xp0 + k);
            short8 qa1 = *(const short8*)(xp1 + k);
            short8 b0 = *(const short8*)(wp0 + k);
            short8 b1 = *(const short8*)(wp1 + k);
            short8 b2 = *(const short8*)(wp2 + k);
            short8 b3 = *(const short8*)(wp3 + k);
            a00 = mfma16(qa0, b0, a00); a01 = mfma16(qa0, b1, a01);
            a02 = mfma16(qa0, b2, a02); a03 = mfma16(qa0, b3, a03);
            a10 = mfma16(qa1, b0, a10); a11 = mfma16(qa1, b1, a11);
            a12 = mfma16(qa1, b2, a12); a13 = mfma16(qa1, b3, a13);
        }
        unsigned short* vb = VsT + (size_t)b * 131072;
        const int m0 = mt2 * 32 + quad * 4;
        f32x4 accs0[4] = {a00, a01, a02, a03};
        f32x4 accs1[4] = {a10, a11, a12, a13};
#pragma unroll
        for (int j = 0; j < 4; ++j) {
            const int c = nt4 * 64 + j * 16 + r16;
            const float bias = 16.f * bv[c];
#pragma unroll
            for (int r = 0; r < 4; ++r) {
                vb[(size_t)c * 256 + m0 + r]      = f2bf(accs0[j][r] + bias);
                vb[(size_t)c * 256 + m0 + 16 + r] = f2bf(accs1[j][r] + bias);
            }
        }
    }
}

__global__ void __launch_bounds__(256, 2)
score_softmax(const unsigned short* __restrict__ QK,
              unsigned short* __restrict__ Amat)
{
    __shared__ float S[16][257];
    const int b = blockIdx.y, strip = blockIdx.x;
    const int w = threadIdx.x >> 6, lane = threadIdx.x & 63;
    const int quad = lane >> 4, r16 = lane & 15;

    {
        const unsigned short* qp = QK + (size_t)(b * 256 + strip * 16 + r16) * 1024 + quad * 8;
        const unsigned short* kp0 = QK + (size_t)(b * 256 + w * 64 + r16) * 1024 + 512 + quad * 8;
        const unsigned short* kp1 = kp0 + 16 * 1024;
        const unsigned short* kp2 = kp0 + 32 * 1024;
        const unsigned short* kp3 = kp0 + 48 * 1024;

        f32x4 a0 = {0,0,0,0}, a1 = a0, a2 = a0, a3 = a0;
#pragma unroll 4
        for (int k = 0; k < 512; k += 32) {
            short8 qa = *(const short8*)(qp + k);
            short8 b0 = *(const short8*)(kp0 + k);
            short8 b1 = *(const short8*)(kp1 + k);
            short8 b2 = *(const short8*)(kp2 + k);
            short8 b3 = *(const short8*)(kp3 + k);
            a0 = mfma16(qa, b0, a0); a1 = mfma16(qa, b1, a1);
            a2 = mfma16(qa, b2, a2); a3 = mfma16(qa, b3, a3);
        }
        f32x4 accs[4] = {a0, a1, a2, a3};
#pragma unroll
        for (int j = 0; j < 4; ++j) {
            const int col = w * 64 + j * 16 + r16;
#pragma unroll
            for (int r = 0; r < 4; ++r)
                S[quad * 4 + r][col] = accs[j][r];
        }
    }
    __syncthreads();

    {
        const int t = threadIdx.x;
        const int r = t >> 4, idx = t & 15;
        float v[16];
        float mx = -3.4e38f;
#pragma unroll
        for (int j = 0; j < 16; ++j) {
            v[j] = S[r][idx * 16 + j] * 0.044194173824159216f;
            mx = fmaxf(mx, v[j]);
        }
        mx = fmaxf(mx, __shfl_xor(mx, 1));
        mx = fmaxf(mx, __shfl_xor(mx, 2));
        mx = fmaxf(mx, __shfl_xor(mx, 4));
        mx = fmaxf(mx, __shfl_xor(mx, 8));
        float sum = 0.f;
#pragma unroll
        for (int j = 0; j < 16; ++j) { v[j] = __expf(v[j] - mx); sum += v[j]; }
        sum += __shfl_xor(sum, 1);
        sum += __shfl_xor(sum, 2);
        sum += __shfl_xor(sum, 4);
        sum += __shfl_xor(sum, 8);
        const float inv = 1.f / sum;
        unsigned short* ap = Amat + (size_t)b * 65536 + (size_t)(strip * 16 + r) * 256 + idx * 16;
#pragma unroll
        for (int j = 0; j < 16; j += 4)
            *(ushort4*)(ap + j) = make_ushort4(f2bf(v[j] * inv), f2bf(v[j + 1] * inv),
                                               f2bf(v[j + 2] * inv), f2bf(v[j + 3] * inv));
    }
}

__global__ void __launch_bounds__(256, 4)
av_expand(const unsigned short* __restrict__ Amat,
          const unsigned short* __restrict__ VsT,
          float* __restrict__ out)
{
    __shared__ float osT[64][17];
    const int b = blockIdx.y;
    const int sh = blockIdx.x >> 3;
    const int cq = blockIdx.x & 7;
    const int w = threadIdx.x >> 6, lane = threadIdx.x & 63;
    const int quad = lane >> 4, r16 = lane & 15;

    {
        const unsigned short* ap = Amat + (size_t)b * 65536 + (size_t)(sh * 16 + r16) * 256 + quad * 8;
        const unsigned short* vp = VsT + (size_t)b * 131072 +
                                   (size_t)(cq * 64 + w * 16 + r16) * 256 + quad * 8;
        f32x4 acc = {0.f, 0.f, 0.f, 0.f};
#pragma unroll
        for (int k = 0; k < 256; k += 32) {
            short8 a0 = *(const short8*)(ap + k);
            short8 b0 = *(const short8*)(vp + k);
            acc = mfma16(a0, b0, acc);
        }
#pragma unroll
        for (int r = 0; r < 4; ++r)
            osT[w * 16 + r16][quad * 4 + r] = acc[r];
    }
    __syncthreads();

    {
        const int t = threadIdx.x;
        const int ch4 = t >> 6;
        const int j = t & 63;
        const int n = j >> 2;
        float* obase = out + (size_t)(b * 512 + cq * 64) * 4096 + sh * 256 + j * 4;
#pragma unroll
        for (int it = 0; it < 16; ++it) {
            const int ch = it * 4 + ch4;
            const float v = osT[ch][n];
            *(float4*)(obase + (size_t)ch * 4096) = make_float4(v, v, v, v);
        }
    }
}

extern "C" void kernel_launch(void* const* d_in, const int* in_sizes, int n_in,
                              void* d_out, int out_size, void* d_ws, size_t ws_size,
                              hipStream_t stream) {
    const float* x  = (const float*)d_in[0];
    const float* Wq = (const float*)d_in[1];
    const float* bq = (const float*)d_in[2];
    const float* Wk = (const float*)d_in[3];
    const float* bk = (const float*)d_in[4];
    const float* Wv = (const float*)d_in[5];
    const float* bv = (const float*)d_in[6];
    float* out = (float*)d_out;

    unsigned short* Wb   = (unsigned short*)d_ws;    // 786432 shorts (Wq|Wk|Wv)
    unsigned short* xavg = Wb + 786432;              // 1048576
    unsigned short* xsum = xavg + 1048576;           // 1048576
    unsigned short* QK   = xsum + 1048576;           // 2097152 (2048x1024)
    unsigned short* VsT  = QK + 2097152;             // 1048576 (8 x 512x256)
    unsigned short* Amat = VsT + 1048576;            // 524288  (8 x 256x256)

    void* args[] = {
        (void*)&x, (void*)&Wq, (void*)&Wk, (void*)&Wv,
        (void*)&bq, (void*)&bk, (void*)&bv, (void*)&out,
        (void*)&Wb, (void*)&xavg, (void*)&xsum,
        (void*)&QK, (void*)&VsT, (void*)&Amat
    };
    hipError_t err = hipLaunchCooperativeKernel((const void*)mega_kernel,
                                                dim3(NBLK), dim3(256),
                                                args, 0, stream);
    if (err != hipSuccess) {
        // Fallback: proven 4-kernel pipeline.
        prep_kernel<<<4480, 256, 0, stream>>>(x, Wq, Wk, Wv, xavg, xsum, Wb);
        proj_gemm<<<384, 256, 0, stream>>>(xavg, xsum, Wb, bq, bk, bv, QK, VsT);
        score_softmax<<<dim3(16, 8), 256, 0, stream>>>(QK, Amat);
        av_expand<<<dim3(128, 8), 256, 0, stream>>>(Amat, VsT, out);
    }
}

// Round 4
// 184.970 us; speedup vs baseline: 5.6028x; 5.6028x over previous
//
#include <hip/hip_runtime.h>

typedef __attribute__((ext_vector_type(8))) short short8;
typedef __attribute__((ext_vector_type(4))) float f32x4;

__device__ __forceinline__ unsigned short f2bf(float f) {
    union { float f; unsigned int i; } v; v.f = f;
    unsigned int x = v.i;
    return (unsigned short)((x + 0x7FFFu + ((x >> 16) & 1u)) >> 16); // RNE, finite inputs
}
__device__ __forceinline__ f32x4 mfma16(short8 a, short8 b, f32x4 c) {
    return __builtin_amdgcn_mfma_f32_16x16x32_bf16(a, b, c, 0, 0, 0);
}

// ---------------------------------------------------------------------------
// K1: fused input prep, fully-coalesced loads (1 KB contiguous per wave instr).
// Blocks 0..4095: per (b,c) plane of fp32 x. Blocks 4096..4479: W -> bf16.
// (unchanged from the 180.4 us verified pipeline)
// ---------------------------------------------------------------------------
__global__ void prep_kernel(const float* __restrict__ x,
                            const float* __restrict__ Wq,
                            const float* __restrict__ Wk,
                            const float* __restrict__ Wv,
                            unsigned short* __restrict__ xavg,
                            unsigned short* __restrict__ xsum,
                            unsigned short* __restrict__ Wb)
{
    const int blk = blockIdx.x;
    const int t = threadIdx.x;
    if (blk >= 4096) {                      // weight conversion
        const int f = (blk - 4096) * 512 + t;   // float4 id; pair (f, f+256)
        const int m = f >> 16;                  // 65536 float4 per matrix
        const int o = f & 65535;
        const float4* s4 = (const float4*)((m == 0) ? Wq : (m == 1) ? Wk : Wv);
        float4 a = s4[o];
        float4 b = s4[o + 256];
        ushort4* d4 = (ushort4*)(Wb + (size_t)m * 262144);
        d4[o]       = make_ushort4(f2bf(a.x), f2bf(a.y), f2bf(a.z), f2bf(a.w));
        d4[o + 256] = make_ushort4(f2bf(b.x), f2bf(b.y), f2bf(b.z), f2bf(b.w));
        return;
    }
    const int b = blk >> 9;                 // plane = b*512 + c
    const int c = blk & 511;

    const float4* x4 = (const float4*)(x + (size_t)blk * 4096);
    float4 f0 = x4[t], f1 = x4[t + 256], f2 = x4[t + 512], f3 = x4[t + 768];

    __shared__ float part2[1024];
    part2[t]       = f0.x + f0.y + f0.z + f0.w;
    part2[t + 256] = f1.x + f1.y + f1.z + f1.w;
    part2[t + 512] = f2.x + f2.y + f2.z + f2.w;
    part2[t + 768] = f3.x + f3.y + f3.z + f3.w;
    __syncthreads();

    // xsum: group g = t (16 consecutive flat pixels)
    {
        const int base = 16 * (t >> 2) + 4 * (t & 3);
        float4 q = *(const float4*)&part2[base];
        xsum[((size_t)b * 256 + t) * 512 + c] = f2bf(q.x + q.y + q.z + q.w);
    }
    // xavg: spatial block n = t = bh*16+bw
    {
        const int bh = t >> 4, bw = t & 15;
        float m = (part2[(bh * 4 + 0) * 16 + bw] + part2[(bh * 4 + 1) * 16 + bw] +
                   part2[(bh * 4 + 2) * 16 + bw] + part2[(bh * 4 + 3) * 16 + bw]) * 0.0625f;
        xavg[((size_t)b * 256 + t) * 512 + c] = f2bf(m);
    }
}

// ---------------------------------------------------------------------------
// K2: joint projection (384 blocks). 32x64 tile/wave, 6 loads -> 8 MFMAs.
// (unchanged from the 180.4 us verified pipeline)
// ---------------------------------------------------------------------------
__global__ void __launch_bounds__(256, 2)
proj_gemm(const unsigned short* __restrict__ xavg,
          const unsigned short* __restrict__ xsum,
          const unsigned short* __restrict__ Wb,
          const float* __restrict__ bq,
          const float* __restrict__ bk,
          const float* __restrict__ bv,
          unsigned short* __restrict__ QK,
          unsigned short* __restrict__ VsT)
{
    const int blk = blockIdx.x;
    const int lane = threadIdx.x & 63, quad = lane >> 4, r16 = lane & 15;
    const int w = threadIdx.x >> 6;

    if (blk < 256) {                        // ---- QK projection ----
        const int wave = blk * 4 + w;       // 0..1023
        const int mt2 = wave >> 4;          // 0..63 (32-row tiles)
        const int nt4 = wave & 15;          // 0..15 (64-col tiles)
        const unsigned short* xp0 = xavg + (size_t)(mt2 * 32 + r16) * 512 + quad * 8;
        const unsigned short* xp1 = xp0 + 16 * 512;
        const unsigned short* wp0 = Wb + (size_t)(nt4 * 64 + r16) * 512 + quad * 8;
        const unsigned short* wp1 = wp0 + 16 * 512;
        const unsigned short* wp2 = wp0 + 32 * 512;
        const unsigned short* wp3 = wp0 + 48 * 512;

        f32x4 a00 = {0,0,0,0}, a01 = a00, a02 = a00, a03 = a00;
        f32x4 a10 = a00, a11 = a00, a12 = a00, a13 = a00;
#pragma unroll 4
        for (int k = 0; k < 512; k += 32) {
            short8 qa0 = *(const short8*)(xp0 + k);
            short8 qa1 = *(const short8*)(xp1 + k);
            short8 b0 = *(const short8*)(wp0 + k);
            short8 b1 = *(const short8*)(wp1 + k);
            short8 b2 = *(const short8*)(wp2 + k);
            short8 b3 = *(const short8*)(wp3 + k);
            a00 = mfma16(qa0, b0, a00); a01 = mfma16(qa0, b1, a01);
            a02 = mfma16(qa0, b2, a02); a03 = mfma16(qa0, b3, a03);
            a10 = mfma16(qa1, b0, a10); a11 = mfma16(qa1, b1, a11);
            a12 = mfma16(qa1, b2, a12); a13 = mfma16(qa1, b3, a13);
        }
        const int row0 = mt2 * 32 + quad * 4;
        f32x4 accs0[4] = {a00, a01, a02, a03};
        f32x4 accs1[4] = {a10, a11, a12, a13};
#pragma unroll
        for (int j = 0; j < 4; ++j) {
            const int c = nt4 * 64 + j * 16 + r16;
            const float bias = (c < 512) ? bq[c] : bk[c - 512];
#pragma unroll
            for (int r = 0; r < 4; ++r) {
                QK[(size_t)(row0 + r) * 1024 + c]      = f2bf(accs0[j][r] + bias);
                QK[(size_t)(row0 + 16 + r) * 1024 + c] = f2bf(accs1[j][r] + bias);
            }
        }
    } else {                                // ---- V projection (transposed) ----
        const int vblk = blk - 256;         // 0..127
        const int b = vblk >> 4;            // 0..7
        const int wave = (vblk & 15) * 4 + w;   // 0..63
        const int mt2 = wave >> 3;          // 0..7
        const int nt4 = wave & 7;           // 0..7
        const unsigned short* xp0 = xsum + (size_t)b * 131072 + (size_t)(mt2 * 32 + r16) * 512 + quad * 8;
        const unsigned short* xp1 = xp0 + 16 * 512;
        const unsigned short* wp0 = Wb + 524288 + (size_t)(nt4 * 64 + r16) * 512 + quad * 8;
        const unsigned short* wp1 = wp0 + 16 * 512;
        const unsigned short* wp2 = wp0 + 32 * 512;
        const unsigned short* wp3 = wp0 + 48 * 512;

        f32x4 a00 = {0,0,0,0}, a01 = a00, a02 = a00, a03 = a00;
        f32x4 a10 = a00, a11 = a00, a12 = a00, a13 = a00;
#pragma unroll 4
        for (int k = 0; k < 512; k += 32) {
            short8 qa0 = *(const short8*)(xp0 + k);
            short8 qa1 = *(const short8*)(xp1 + k);
            short8 b0 = *(const short8*)(wp0 + k);
            short8 b1 = *(const short8*)(wp1 + k);
            short8 b2 = *(const short8*)(wp2 + k);
            short8 b3 = *(const short8*)(wp3 + k);
            a00 = mfma16(qa0, b0, a00); a01 = mfma16(qa0, b1, a01);
            a02 = mfma16(qa0, b2, a02); a03 = mfma16(qa0, b3, a03);
            a10 = mfma16(qa1, b0, a10); a11 = mfma16(qa1, b1, a11);
            a12 = mfma16(qa1, b2, a12); a13 = mfma16(qa1, b3, a13);
        }
        unsigned short* vb = VsT + (size_t)b * 131072;
        const int m0 = mt2 * 32 + quad * 4;
        f32x4 accs0[4] = {a00, a01, a02, a03};
        f32x4 accs1[4] = {a10, a11, a12, a13};
#pragma unroll
        for (int j = 0; j < 4; ++j) {
            const int c = nt4 * 64 + j * 16 + r16;
            const float bias = 16.f * bv[c];
#pragma unroll
            for (int r = 0; r < 4; ++r) {
                vb[(size_t)c * 256 + m0 + r]      = f2bf(accs0[j][r] + bias);
                vb[(size_t)c * 256 + m0 + 16 + r] = f2bf(accs1[j][r] + bias);
            }
        }
    }
}

// ---------------------------------------------------------------------------
// K3+K4 merged: scores + softmax + AV + expand in one kernel.
// Grid (32, 8) = 256 blocks (one/CU): bx = strip*2 + chalf.
// Phase 1: 16x256 scores for this strip (both c-half blocks duplicate this —
//          +0.5 GFLOP total, trivial) into LDS S.
// Phase 2: softmax (16 thr/row) -> bf16 A kept in LDS (no Amat round-trip).
// Phase 3: AV for this block's 256-channel half: per wave 4x (16c x 16n)
//          tiles, K=256; A-frags from LDS, VsT-frags from global (L2-hot).
// Phase 4: transpose via osT, fully-contiguous 1 KB/thread expanded write.
// vs old K3 (128 blocks, half of CUs idle) + K4 (extra kernel boundary).
// ---------------------------------------------------------------------------
__global__ void __launch_bounds__(256, 2)
score_av(const unsigned short* __restrict__ QK,
         const unsigned short* __restrict__ VsT,
         float* __restrict__ out)
{
    __shared__ union {
        float S[16][257];
        float osT[256][17];
    } u;
    __shared__ __align__(16) unsigned short Abf[16][264];   // +8 pad: row stride 528 B

    const int b = blockIdx.y;
    const int strip = blockIdx.x >> 1;      // 0..15
    const int chalf = blockIdx.x & 1;       // 0..1: which 256-channel half
    const int w = threadIdx.x >> 6, lane = threadIdx.x & 63;
    const int quad = lane >> 4, r16 = lane & 15;

    // ---- Phase 1: scores (identical math to verified K3) ----
    {
        const unsigned short* qp = QK + (size_t)(b * 256 + strip * 16 + r16) * 1024 + quad * 8;
        const unsigned short* kp0 = QK + (size_t)(b * 256 + w * 64 + r16) * 1024 + 512 + quad * 8;
        const unsigned short* kp1 = kp0 + 16 * 1024;
        const unsigned short* kp2 = kp0 + 32 * 1024;
        const unsigned short* kp3 = kp0 + 48 * 1024;

        f32x4 a0 = {0,0,0,0}, a1 = a0, a2 = a0, a3 = a0;
#pragma unroll 4
        for (int k = 0; k < 512; k += 32) {
            short8 qa = *(const short8*)(qp + k);
            short8 b0 = *(const short8*)(kp0 + k);
            short8 b1 = *(const short8*)(kp1 + k);
            short8 b2 = *(const short8*)(kp2 + k);
            short8 b3 = *(const short8*)(kp3 + k);
            a0 = mfma16(qa, b0, a0); a1 = mfma16(qa, b1, a1);
            a2 = mfma16(qa, b2, a2); a3 = mfma16(qa, b3, a3);
        }
        f32x4 accs[4] = {a0, a1, a2, a3};
#pragma unroll
        for (int j = 0; j < 4; ++j) {
            const int col = w * 64 + j * 16 + r16;
#pragma unroll
            for (int r = 0; r < 4; ++r)
                u.S[quad * 4 + r][col] = accs[j][r];
        }
    }
    __syncthreads();

    // ---- Phase 2: softmax -> bf16 A in LDS ----
    {
        const int t = threadIdx.x;
        const int r = t >> 4, idx = t & 15;     // row r, cols idx*16..+15
        float v[16];
        float mx = -3.4e38f;
#pragma unroll
        for (int j = 0; j < 16; ++j) {
            v[j] = u.S[r][idx * 16 + j] * 0.044194173824159216f;
            mx = fmaxf(mx, v[j]);
        }
        mx = fmaxf(mx, __shfl_xor(mx, 1));
        mx = fmaxf(mx, __shfl_xor(mx, 2));
        mx = fmaxf(mx, __shfl_xor(mx, 4));
        mx = fmaxf(mx, __shfl_xor(mx, 8));
        float sum = 0.f;
#pragma unroll
        for (int j = 0; j < 16; ++j) { v[j] = __expf(v[j] - mx); sum += v[j]; }
        sum += __shfl_xor(sum, 1);
        sum += __shfl_xor(sum, 2);
        sum += __shfl_xor(sum, 4);
        sum += __shfl_xor(sum, 8);
        const float inv = 1.f / sum;
        unsigned short* ap = &Abf[r][idx * 16];
#pragma unroll
        for (int j = 0; j < 16; j += 4)
            *(ushort4*)(ap + j) = make_ushort4(f2bf(v[j] * inv), f2bf(v[j + 1] * inv),
                                               f2bf(v[j + 2] * inv), f2bf(v[j + 3] * inv));
    }
    __syncthreads();

    // ---- Phase 3: AV for this c-half (per wave: 4 tiles of 16c x 16n) ----
    {
        f32x4 acc0 = {0,0,0,0}, acc1 = acc0, acc2 = acc0, acc3 = acc0;
        const unsigned short* vbase = VsT + (size_t)b * 131072 +
                                      (size_t)(chalf * 256 + w * 64 + r16) * 256 + quad * 8;
        const unsigned short* vp0 = vbase;
        const unsigned short* vp1 = vbase + 16 * 256;
        const unsigned short* vp2 = vbase + 32 * 256;
        const unsigned short* vp3 = vbase + 48 * 256;
#pragma unroll
        for (int kk = 0; kk < 256; kk += 32) {
            short8 a = *(const short8*)(&Abf[r16][kk + quad * 8]);
            short8 b0 = *(const short8*)(vp0 + kk);
            short8 b1 = *(const short8*)(vp1 + kk);
            short8 b2 = *(const short8*)(vp2 + kk);
            short8 b3 = *(const short8*)(vp3 + kk);
            acc0 = mfma16(a, b0, acc0); acc1 = mfma16(a, b1, acc1);
            acc2 = mfma16(a, b2, acc2); acc3 = mfma16(a, b3, acc3);
        }
        __syncthreads();                    // S dead; osT aliases it
        f32x4 accs[4] = {acc0, acc1, acc2, acc3};
#pragma unroll
        for (int i = 0; i < 4; ++i) {
            const int cl = w * 64 + i * 16 + r16;
#pragma unroll
            for (int r = 0; r < 4; ++r)
                u.osT[cl][quad * 4 + r] = accs[i][r];
        }
    }
    __syncthreads();

    // ---- Phase 4: expanded write, 1 KB contiguous per thread ----
    {
        const int t = threadIdx.x;          // t = local channel 0..255
        const float* orow = &u.osT[t][0];
        float* obase = out + (size_t)(b * 512 + chalf * 256 + t) * 4096 + strip * 256;
#pragma unroll
        for (int n = 0; n < 16; ++n) {
            const float v = orow[n];
            float4 v4 = make_float4(v, v, v, v);
            *(float4*)(obase + n * 16)      = v4;
            *(float4*)(obase + n * 16 + 4)  = v4;
            *(float4*)(obase + n * 16 + 8)  = v4;
            *(float4*)(obase + n * 16 + 12) = v4;
        }
    }
}

extern "C" void kernel_launch(void* const* d_in, const int* in_sizes, int n_in,
                              void* d_out, int out_size, void* d_ws, size_t ws_size,
                              hipStream_t stream) {
    const float* x  = (const float*)d_in[0];
    const float* Wq = (const float*)d_in[1];
    const float* bq = (const float*)d_in[2];
    const float* Wk = (const float*)d_in[3];
    const float* bk = (const float*)d_in[4];
    const float* Wv = (const float*)d_in[5];
    const float* bv = (const float*)d_in[6];
    float* out = (float*)d_out;

    // All scratch in d_ws; fully written before read each call.
    unsigned short* Wb   = (unsigned short*)d_ws;    // 786432 shorts (Wq|Wk|Wv)
    unsigned short* xavg = Wb + 786432;              // 1048576
    unsigned short* xsum = xavg + 1048576;           // 1048576
    unsigned short* QK   = xsum + 1048576;           // 2097152 (2048x1024)
    unsigned short* VsT  = QK + 2097152;             // 1048576 (8 x 512x256)

    // K1: plane reductions (4096 blocks) + weight convert (384 blocks)
    prep_kernel<<<4480, 256, 0, stream>>>(x, Wq, Wk, Wv, xavg, xsum, Wb);
    // K2: QK = xavg @ [Wq;Wk]^T + bias  AND  VsT = (xsum @ Wv^T + 16*bv)^T
    proj_gemm<<<384, 256, 0, stream>>>(xavg, xsum, Wb, bq, bk, bv, QK, VsT);
    // K3+K4 merged: scores + softmax + AV + expanded write (256 blocks)
    score_av<<<dim3(32, 8), 256, 0, stream>>>(QK, VsT, out);
}

// Round 5
// 172.527 us; speedup vs baseline: 6.0069x; 1.0721x over previous
//
#include <hip/hip_runtime.h>

typedef __attribute__((ext_vector_type(8))) short short8;
typedef __attribute__((ext_vector_type(4))) float f32x4;

__device__ __forceinline__ unsigned short f2bf(float f) {
    union { float f; unsigned int i; } v; v.f = f;
    unsigned int x = v.i;
    return (unsigned short)((x + 0x7FFFu + ((x >> 16) & 1u)) >> 16); // RNE, finite inputs
}
__device__ __forceinline__ f32x4 mfma16(short8 a, short8 b, f32x4 c) {
    return __builtin_amdgcn_mfma_f32_16x16x32_bf16(a, b, c, 0, 0, 0);
}

// ---------------------------------------------------------------------------
// K1: fused input prep, fully-coalesced loads (1 KB contiguous per wave instr).
// Blocks 0..4095: per (b,c) plane of fp32 x. Blocks 4096..4479: W -> bf16.
// (unchanged from the 180.4 us verified pipeline)
// ---------------------------------------------------------------------------
__global__ void prep_kernel(const float* __restrict__ x,
                            const float* __restrict__ Wq,
                            const float* __restrict__ Wk,
                            const float* __restrict__ Wv,
                            unsigned short* __restrict__ xavg,
                            unsigned short* __restrict__ xsum,
                            unsigned short* __restrict__ Wb)
{
    const int blk = blockIdx.x;
    const int t = threadIdx.x;
    if (blk >= 4096) {                      // weight conversion
        const int f = (blk - 4096) * 512 + t;   // float4 id; pair (f, f+256)
        const int m = f >> 16;                  // 65536 float4 per matrix
        const int o = f & 65535;
        const float4* s4 = (const float4*)((m == 0) ? Wq : (m == 1) ? Wk : Wv);
        float4 a = s4[o];
        float4 b = s4[o + 256];
        ushort4* d4 = (ushort4*)(Wb + (size_t)m * 262144);
        d4[o]       = make_ushort4(f2bf(a.x), f2bf(a.y), f2bf(a.z), f2bf(a.w));
        d4[o + 256] = make_ushort4(f2bf(b.x), f2bf(b.y), f2bf(b.z), f2bf(b.w));
        return;
    }
    const int b = blk >> 9;                 // plane = b*512 + c
    const int c = blk & 511;

    const float4* x4 = (const float4*)(x + (size_t)blk * 4096);
    float4 f0 = x4[t], f1 = x4[t + 256], f2 = x4[t + 512], f3 = x4[t + 768];

    __shared__ float part2[1024];
    part2[t]       = f0.x + f0.y + f0.z + f0.w;
    part2[t + 256] = f1.x + f1.y + f1.z + f1.w;
    part2[t + 512] = f2.x + f2.y + f2.z + f2.w;
    part2[t + 768] = f3.x + f3.y + f3.z + f3.w;
    __syncthreads();

    // xsum: group g = t (16 consecutive flat pixels)
    {
        const int base = 16 * (t >> 2) + 4 * (t & 3);
        float4 q = *(const float4*)&part2[base];
        xsum[((size_t)b * 256 + t) * 512 + c] = f2bf(q.x + q.y + q.z + q.w);
    }
    // xavg: spatial block n = t = bh*16+bw
    {
        const int bh = t >> 4, bw = t & 15;
        float m = (part2[(bh * 4 + 0) * 16 + bw] + part2[(bh * 4 + 1) * 16 + bw] +
                   part2[(bh * 4 + 2) * 16 + bw] + part2[(bh * 4 + 3) * 16 + bw]) * 0.0625f;
        xavg[((size_t)b * 256 + t) * 512 + c] = f2bf(m);
    }
}

// ---------------------------------------------------------------------------
// K2: joint projection, re-tiled for occupancy. 32x32 tile/wave (4 loads ->
// 4 MFMAs), grid exactly 768 blocks = 3 blocks/CU = 12 waves/CU (was 384
// blocks = 1.5/CU = 6 waves/CU, latency-hiding-starved on L2-hot operands).
// Per-output K-accumulation order identical to the 32x64 version ->
// bit-identical results.
// Blocks 0..511:  QK[2048x1024] = xavg @ [Wq;Wk]^T + [bq;bk].
// Blocks 512..767: VsT[b][c][m] = (xsum[b] @ Wv^T + 16*bv)^T.
// ---------------------------------------------------------------------------
__global__ void __launch_bounds__(256, 3)
proj_gemm(const unsigned short* __restrict__ xavg,
          const unsigned short* __restrict__ xsum,
          const unsigned short* __restrict__ Wb,
          const float* __restrict__ bq,
          const float* __restrict__ bk,
          const float* __restrict__ bv,
          unsigned short* __restrict__ QK,
          unsigned short* __restrict__ VsT)
{
    const int blk = blockIdx.x;
    const int lane = threadIdx.x & 63, quad = lane >> 4, r16 = lane & 15;
    const int w = threadIdx.x >> 6;

    if (blk < 512) {                        // ---- QK projection ----
        const int wave = blk * 4 + w;       // 0..2047
        const int mt = wave >> 5;           // 0..63 (32-row tiles)
        const int nt = wave & 31;           // 0..31 (32-col tiles)
        const unsigned short* xp0 = xavg + (size_t)(mt * 32 + r16) * 512 + quad * 8;
        const unsigned short* xp1 = xp0 + 16 * 512;
        const unsigned short* wp0 = Wb + (size_t)(nt * 32 + r16) * 512 + quad * 8;
        const unsigned short* wp1 = wp0 + 16 * 512;

        f32x4 a00 = {0,0,0,0}, a01 = a00, a10 = a00, a11 = a00;
#pragma unroll 4
        for (int k = 0; k < 512; k += 32) {
            short8 qa0 = *(const short8*)(xp0 + k);
            short8 qa1 = *(const short8*)(xp1 + k);
            short8 b0 = *(const short8*)(wp0 + k);
            short8 b1 = *(const short8*)(wp1 + k);
            a00 = mfma16(qa0, b0, a00); a01 = mfma16(qa0, b1, a01);
            a10 = mfma16(qa1, b0, a10); a11 = mfma16(qa1, b1, a11);
        }
        const int row0 = mt * 32 + quad * 4;
        f32x4 accs0[2] = {a00, a01};
        f32x4 accs1[2] = {a10, a11};
#pragma unroll
        for (int j = 0; j < 2; ++j) {
            const int c = nt * 32 + j * 16 + r16;
            const float bias = (c < 512) ? bq[c] : bk[c - 512];
#pragma unroll
            for (int r = 0; r < 4; ++r) {
                QK[(size_t)(row0 + r) * 1024 + c]      = f2bf(accs0[j][r] + bias);
                QK[(size_t)(row0 + 16 + r) * 1024 + c] = f2bf(accs1[j][r] + bias);
            }
        }
    } else {                                // ---- V projection (transposed) ----
        const int vblk = blk - 512;         // 0..255
        const int b = vblk >> 5;            // 0..7
        const int wib = (vblk & 31) * 4 + w;    // 0..127
        const int mt2 = wib >> 4;           // 0..7 (32-row tiles of 256)
        const int nt = wib & 15;            // 0..15 (32-col tiles of 512)
        const unsigned short* xp0 = xsum + (size_t)b * 131072 + (size_t)(mt2 * 32 + r16) * 512 + quad * 8;
        const unsigned short* xp1 = xp0 + 16 * 512;
        const unsigned short* wp0 = Wb + 524288 + (size_t)(nt * 32 + r16) * 512 + quad * 8;
        const unsigned short* wp1 = wp0 + 16 * 512;

        f32x4 a00 = {0,0,0,0}, a01 = a00, a10 = a00, a11 = a00;
#pragma unroll 4
        for (int k = 0; k < 512; k += 32) {
            short8 qa0 = *(const short8*)(xp0 + k);
            short8 qa1 = *(const short8*)(xp1 + k);
            short8 b0 = *(const short8*)(wp0 + k);
            short8 b1 = *(const short8*)(wp1 + k);
            a00 = mfma16(qa0, b0, a00); a01 = mfma16(qa0, b1, a01);
            a10 = mfma16(qa1, b0, a10); a11 = mfma16(qa1, b1, a11);
        }
        unsigned short* vb = VsT + (size_t)b * 131072;
        const int m0 = mt2 * 32 + quad * 4;
        f32x4 accs0[2] = {a00, a01};
        f32x4 accs1[2] = {a10, a11};
#pragma unroll
        for (int j = 0; j < 2; ++j) {
            const int c = nt * 32 + j * 16 + r16;
            const float bias = 16.f * bv[c];
#pragma unroll
            for (int r = 0; r < 4; ++r) {
                vb[(size_t)c * 256 + m0 + r]      = f2bf(accs0[j][r] + bias);
                vb[(size_t)c * 256 + m0 + 16 + r] = f2bf(accs1[j][r] + bias);
            }
        }
    }
}

// ---------------------------------------------------------------------------
// K3+K4 merged: scores + softmax + AV + expand in one kernel.
// Grid (32, 8) = 256 blocks (one/CU): bx = strip*2 + chalf.
// Phase 4 FIXED: wave-coalesced stores (1 KB contiguous per wave instruction,
// like the verified old K4) instead of per-thread rows (64 lanes scattered
// across 16 KB-strided lines — the round-4 regression).
// ---------------------------------------------------------------------------
__global__ void __launch_bounds__(256, 2)
score_av(const unsigned short* __restrict__ QK,
         const unsigned short* __restrict__ VsT,
         float* __restrict__ out)
{
    __shared__ union {
        float S[16][257];
        float osT[256][17];
    } u;
    __shared__ __align__(16) unsigned short Abf[16][264];   // +8 pad: row stride 528 B

    const int b = blockIdx.y;
    const int strip = blockIdx.x >> 1;      // 0..15
    const int chalf = blockIdx.x & 1;       // 0..1: which 256-channel half
    const int w = threadIdx.x >> 6, lane = threadIdx.x & 63;
    const int quad = lane >> 4, r16 = lane & 15;

    // ---- Phase 1: scores (identical math to verified K3) ----
    {
        const unsigned short* qp = QK + (size_t)(b * 256 + strip * 16 + r16) * 1024 + quad * 8;
        const unsigned short* kp0 = QK + (size_t)(b * 256 + w * 64 + r16) * 1024 + 512 + quad * 8;
        const unsigned short* kp1 = kp0 + 16 * 1024;
        const unsigned short* kp2 = kp0 + 32 * 1024;
        const unsigned short* kp3 = kp0 + 48 * 1024;

        f32x4 a0 = {0,0,0,0}, a1 = a0, a2 = a0, a3 = a0;
#pragma unroll 4
        for (int k = 0; k < 512; k += 32) {
            short8 qa = *(const short8*)(qp + k);
            short8 b0 = *(const short8*)(kp0 + k);
            short8 b1 = *(const short8*)(kp1 + k);
            short8 b2 = *(const short8*)(kp2 + k);
            short8 b3 = *(const short8*)(kp3 + k);
            a0 = mfma16(qa, b0, a0); a1 = mfma16(qa, b1, a1);
            a2 = mfma16(qa, b2, a2); a3 = mfma16(qa, b3, a3);
        }
        f32x4 accs[4] = {a0, a1, a2, a3};
#pragma unroll
        for (int j = 0; j < 4; ++j) {
            const int col = w * 64 + j * 16 + r16;
#pragma unroll
            for (int r = 0; r < 4; ++r)
                u.S[quad * 4 + r][col] = accs[j][r];
        }
    }
    __syncthreads();

    // ---- Phase 2: softmax -> bf16 A in LDS ----
    {
        const int t = threadIdx.x;
        const int r = t >> 4, idx = t & 15;     // row r, cols idx*16..+15
        float v[16];
        float mx = -3.4e38f;
#pragma unroll
        for (int j = 0; j < 16; ++j) {
            v[j] = u.S[r][idx * 16 + j] * 0.044194173824159216f;
            mx = fmaxf(mx, v[j]);
        }
        mx = fmaxf(mx, __shfl_xor(mx, 1));
        mx = fmaxf(mx, __shfl_xor(mx, 2));
        mx = fmaxf(mx, __shfl_xor(mx, 4));
        mx = fmaxf(mx, __shfl_xor(mx, 8));
        float sum = 0.f;
#pragma unroll
        for (int j = 0; j < 16; ++j) { v[j] = __expf(v[j] - mx); sum += v[j]; }
        sum += __shfl_xor(sum, 1);
        sum += __shfl_xor(sum, 2);
        sum += __shfl_xor(sum, 4);
        sum += __shfl_xor(sum, 8);
        const float inv = 1.f / sum;
        unsigned short* ap = &Abf[r][idx * 16];
#pragma unroll
        for (int j = 0; j < 16; j += 4)
            *(ushort4*)(ap + j) = make_ushort4(f2bf(v[j] * inv), f2bf(v[j + 1] * inv),
                                               f2bf(v[j + 2] * inv), f2bf(v[j + 3] * inv));
    }
    __syncthreads();

    // ---- Phase 3: AV for this c-half (per wave: 4 tiles of 16c x 16n) ----
    {
        f32x4 acc0 = {0,0,0,0}, acc1 = acc0, acc2 = acc0, acc3 = acc0;
        const unsigned short* vbase = VsT + (size_t)b * 131072 +
                                      (size_t)(chalf * 256 + w * 64 + r16) * 256 + quad * 8;
        const unsigned short* vp0 = vbase;
        const unsigned short* vp1 = vbase + 16 * 256;
        const unsigned short* vp2 = vbase + 32 * 256;
        const unsigned short* vp3 = vbase + 48 * 256;
#pragma unroll
        for (int kk = 0; kk < 256; kk += 32) {
            short8 a = *(const short8*)(&Abf[r16][kk + quad * 8]);
            short8 b0 = *(const short8*)(vp0 + kk);
            short8 b1 = *(const short8*)(vp1 + kk);
            short8 b2 = *(const short8*)(vp2 + kk);
            short8 b3 = *(const short8*)(vp3 + kk);
            acc0 = mfma16(a, b0, acc0); acc1 = mfma16(a, b1, acc1);
            acc2 = mfma16(a, b2, acc2); acc3 = mfma16(a, b3, acc3);
        }
        __syncthreads();                    // S dead; osT aliases it
        f32x4 accs[4] = {acc0, acc1, acc2, acc3};
#pragma unroll
        for (int i = 0; i < 4; ++i) {
            const int cl = w * 64 + i * 16 + r16;
#pragma unroll
            for (int r = 0; r < 4; ++r)
                u.osT[cl][quad * 4 + r] = accs[i][r];
        }
    }
    __syncthreads();

    // ---- Phase 4: expanded write, 1 KB contiguous per WAVE instruction ----
    // Wave w, iteration it: all 64 lanes write channel ch = it*4 + w,
    // lane j covers float4 index j of the 256-float (1 KB) segment.
    // LDS read osT[ch][j>>2]: 4-lane broadcast groups, conflict-free.
    {
        const int j = threadIdx.x & 63;     // float4 index within segment
        float* obase = out + (size_t)(b * 512 + chalf * 256) * 4096 + strip * 256 + j * 4;
#pragma unroll
        for (int it = 0; it < 64; ++it) {
            const int ch = it * 4 + w;
            const float v = u.osT[ch][j >> 2];
            *(float4*)(obase + (size_t)ch * 4096) = make_float4(v, v, v, v);
        }
    }
}

extern "C" void kernel_launch(void* const* d_in, const int* in_sizes, int n_in,
                              void* d_out, int out_size, void* d_ws, size_t ws_size,
                              hipStream_t stream) {
    const float* x  = (const float*)d_in[0];
    const float* Wq = (const float*)d_in[1];
    const float* bq = (const float*)d_in[2];
    const float* Wk = (const float*)d_in[3];
    const float* bk = (const float*)d_in[4];
    const float* Wv = (const float*)d_in[5];
    const float* bv = (const float*)d_in[6];
    float* out = (float*)d_out;

    // All scratch in d_ws; fully written before read each call.
    unsigned short* Wb   = (unsigned short*)d_ws;    // 786432 shorts (Wq|Wk|Wv)
    unsigned short* xavg = Wb + 786432;              // 1048576
    unsigned short* xsum = xavg + 1048576;           // 1048576
    unsigned short* QK   = xsum + 1048576;           // 2097152 (2048x1024)
    unsigned short* VsT  = QK + 2097152;             // 1048576 (8 x 512x256)

    // K1: plane reductions (4096 blocks) + weight convert (384 blocks)
    prep_kernel<<<4480, 256, 0, stream>>>(x, Wq, Wk, Wv, xavg, xsum, Wb);
    // K2: QK = xavg @ [Wq;Wk]^T + bias  AND  VsT = (xsum @ Wv^T + 16*bv)^T
    proj_gemm<<<768, 256, 0, stream>>>(xavg, xsum, Wb, bq, bk, bv, QK, VsT);
    // K3+K4 merged: scores + softmax + AV + expanded write (256 blocks)
    score_av<<<dim3(32, 8), 256, 0, stream>>>(QK, VsT, out);
}

// Round 7
// 164.541 us; speedup vs baseline: 6.2985x; 1.0485x over previous
//
#include <hip/hip_runtime.h>

typedef __attribute__((ext_vector_type(8))) short short8;
typedef __attribute__((ext_vector_type(4))) float f32x4;

__device__ __forceinline__ unsigned short f2bf(float f) {
    union { float f; unsigned int i; } v; v.f = f;
    unsigned int x = v.i;
    return (unsigned short)((x + 0x7FFFu + ((x >> 16) & 1u)) >> 16); // RNE, finite inputs
}
__device__ __forceinline__ f32x4 mfma16(short8 a, short8 b, f32x4 c) {
    return __builtin_amdgcn_mfma_f32_16x16x32_bf16(a, b, c, 0, 0, 0);
}

// ---------------------------------------------------------------------------
// K1 REWRITE: coalesced-write input prep.
// Old K1: one block per (b,c) plane -> xsum/xavg stores were 2-byte scatters
// at 1 KB stride (64 lines touched per wave-store, ~2.1M L2 sector ops for
// 4 MiB payload). New: block = (b, 16-channel group, half-plane); reduce 4
// channels per phase (8x16B loads/thread in flight), transpose via LDS bf16
// tiles, write xsum/xavg rows as 32 B-contiguous runs (16x sector efficiency).
// Reduction order bit-identical: per-pixel-quad sum -> sum of 4 quads.
// Blocks 0..511: main. Blocks 512..895: Wq|Wk|Wv fp32->bf16 (unchanged).
// ---------------------------------------------------------------------------
__global__ void __launch_bounds__(256, 4)
prep_kernel(const float* __restrict__ x,
            const float* __restrict__ Wq,
            const float* __restrict__ Wk,
            const float* __restrict__ Wv,
            unsigned short* __restrict__ xavg,
            unsigned short* __restrict__ xsum,
            unsigned short* __restrict__ Wb)
{
    const int blk = blockIdx.x;
    const int t = threadIdx.x;
    if (blk >= 512) {                       // weight conversion (unchanged math)
        const int f = (blk - 512) * 512 + t;    // float4 id; pair (f, f+256)
        const int m = f >> 16;                  // 65536 float4 per matrix
        const int o = f & 65535;
        const float4* s4 = (const float4*)((m == 0) ? Wq : (m == 1) ? Wk : Wv);
        float4 a = s4[o];
        float4 b = s4[o + 256];
        ushort4* d4 = (ushort4*)(Wb + (size_t)m * 262144);
        d4[o]       = make_ushort4(f2bf(a.x), f2bf(a.y), f2bf(a.z), f2bf(a.w));
        d4[o + 256] = make_ushort4(f2bf(b.x), f2bf(b.y), f2bf(b.z), f2bf(b.w));
        return;
    }

    const int b    = blk >> 6;              // 0..7
    const int rem  = blk & 63;
    const int cg   = rem >> 1;              // 0..31 : 16-channel group
    const int half = rem & 1;               // 0..1  : h-rows 0..31 / 32..63
    const int c0   = cg * 16;

    __shared__ float part[4][512];          // quad-sums for 4 channels
    __shared__ unsigned short xsT[16][128]; // [c_local][g_local]
    __shared__ unsigned short xaT[16][128]; // [c_local][n_local]

    for (int cg4 = 0; cg4 < 4; ++cg4) {     // 4 phases x 4 channels
        // ---- load 4 half-planes (8x float4 per thread, all issued first) --
        float4 a0, a1, b0, b1, c0v, c1, d0, d1;
        {
            const float* base = x + ((size_t)(b * 512 + c0 + cg4 * 4) * 4096) + half * 2048;
            const float4* p0 = (const float4*)(base);
            const float4* p1 = (const float4*)(base + 4096);
            const float4* p2 = (const float4*)(base + 8192);
            const float4* p3 = (const float4*)(base + 12288);
            a0 = p0[t]; a1 = p0[t + 256];
            b0 = p1[t]; b1 = p1[t + 256];
            c0v = p2[t]; c1 = p2[t + 256];
            d0 = p3[t]; d1 = p3[t + 256];
        }
        part[0][t]       = a0.x + a0.y + a0.z + a0.w;
        part[0][t + 256] = a1.x + a1.y + a1.z + a1.w;
        part[1][t]       = b0.x + b0.y + b0.z + b0.w;
        part[1][t + 256] = b1.x + b1.y + b1.z + b1.w;
        part[2][t]       = c0v.x + c0v.y + c0v.z + c0v.w;
        part[2][t + 256] = c1.x + c1.y + c1.z + c1.w;
        part[3][t]       = d0.x + d0.y + d0.z + d0.w;
        part[3][t + 256] = d1.x + d1.y + d1.z + d1.w;
        __syncthreads();

        if (t < 128) {                      // xsum: group g = 16 consecutive pixels
            const int g = t;
#pragma unroll
            for (int ci = 0; ci < 4; ++ci) {
                float4 q = *(const float4*)&part[ci][4 * g];
                xsT[cg4 * 4 + ci][g] = f2bf(q.x + q.y + q.z + q.w);
            }
        } else {                            // xavg: spatial block n = bh*16+bw (local)
            const int n = t - 128;
            const int bh = n >> 4, bw = n & 15;
#pragma unroll
            for (int ci = 0; ci < 4; ++ci) {
                float m = (part[ci][(bh * 4 + 0) * 16 + bw] + part[ci][(bh * 4 + 1) * 16 + bw] +
                           part[ci][(bh * 4 + 2) * 16 + bw] + part[ci][(bh * 4 + 3) * 16 + bw]) * 0.0625f;
                xaT[cg4 * 4 + ci][n] = f2bf(m);
            }
        }
        __syncthreads();                    // part reused next phase
    }

    // ---- coalesced output: 32 B-contiguous runs of 16 channels per row ----
    {
        const int g = t >> 1, chunk = t & 1;    // row 0..127, 8-channel chunk
        const size_t rowbase = ((size_t)(b * 256) + half * 128 + g) * 512 + c0 + chunk * 8;
        short8 vs, va;
#pragma unroll
        for (int j = 0; j < 8; ++j) {
            vs[j] = (short)xsT[chunk * 8 + j][g];
            va[j] = (short)xaT[chunk * 8 + j][g];
        }
        *(short8*)(xsum + rowbase) = vs;
        *(short8*)(xavg + rowbase) = va;
    }
}

// ---------------------------------------------------------------------------
// K2: joint projection, 32x32 tile/wave, 768 blocks = 3 blocks/CU.
// (unchanged from the 172.5 us verified pipeline)
// ---------------------------------------------------------------------------
__global__ void __launch_bounds__(256, 3)
proj_gemm(const unsigned short* __restrict__ xavg,
          const unsigned short* __restrict__ xsum,
          const unsigned short* __restrict__ Wb,
          const float* __restrict__ bq,
          const float* __restrict__ bk,
          const float* __restrict__ bv,
          unsigned short* __restrict__ QK,
          unsigned short* __restrict__ VsT)
{
    const int blk = blockIdx.x;
    const int lane = threadIdx.x & 63, quad = lane >> 4, r16 = lane & 15;
    const int w = threadIdx.x >> 6;

    if (blk < 512) {                        // ---- QK projection ----
        const int wave = blk * 4 + w;       // 0..2047
        const int mt = wave >> 5;           // 0..63 (32-row tiles)
        const int nt = wave & 31;           // 0..31 (32-col tiles)
        const unsigned short* xp0 = xavg + (size_t)(mt * 32 + r16) * 512 + quad * 8;
        const unsigned short* xp1 = xp0 + 16 * 512;
        const unsigned short* wp0 = Wb + (size_t)(nt * 32 + r16) * 512 + quad * 8;
        const unsigned short* wp1 = wp0 + 16 * 512;

        f32x4 a00 = {0,0,0,0}, a01 = a00, a10 = a00, a11 = a00;
#pragma unroll 4
        for (int k = 0; k < 512; k += 32) {
            short8 qa0 = *(const short8*)(xp0 + k);
            short8 qa1 = *(const short8*)(xp1 + k);
            short8 b0 = *(const short8*)(wp0 + k);
            short8 b1 = *(const short8*)(wp1 + k);
            a00 = mfma16(qa0, b0, a00); a01 = mfma16(qa0, b1, a01);
            a10 = mfma16(qa1, b0, a10); a11 = mfma16(qa1, b1, a11);
        }
        const int row0 = mt * 32 + quad * 4;
        f32x4 accs0[2] = {a00, a01};
        f32x4 accs1[2] = {a10, a11};
#pragma unroll
        for (int j = 0; j < 2; ++j) {
            const int c = nt * 32 + j * 16 + r16;
            const float bias = (c < 512) ? bq[c] : bk[c - 512];
#pragma unroll
            for (int r = 0; r < 4; ++r) {
                QK[(size_t)(row0 + r) * 1024 + c]      = f2bf(accs0[j][r] + bias);
                QK[(size_t)(row0 + 16 + r) * 1024 + c] = f2bf(accs1[j][r] + bias);
            }
        }
    } else {                                // ---- V projection (transposed) ----
        const int vblk = blk - 512;         // 0..255
        const int b = vblk >> 5;            // 0..7
        const int wib = (vblk & 31) * 4 + w;    // 0..127
        const int mt2 = wib >> 4;           // 0..7 (32-row tiles of 256)
        const int nt = wib & 15;            // 0..15 (32-col tiles of 512)
        const unsigned short* xp0 = xsum + (size_t)b * 131072 + (size_t)(mt2 * 32 + r16) * 512 + quad * 8;
        const unsigned short* xp1 = xp0 + 16 * 512;
        const unsigned short* wp0 = Wb + 524288 + (size_t)(nt * 32 + r16) * 512 + quad * 8;
        const unsigned short* wp1 = wp0 + 16 * 512;

        f32x4 a00 = {0,0,0,0}, a01 = a00, a10 = a00, a11 = a00;
#pragma unroll 4
        for (int k = 0; k < 512; k += 32) {
            short8 qa0 = *(const short8*)(xp0 + k);
            short8 qa1 = *(const short8*)(xp1 + k);
            short8 b0 = *(const short8*)(wp0 + k);
            short8 b1 = *(const short8*)(wp1 + k);
            a00 = mfma16(qa0, b0, a00); a01 = mfma16(qa0, b1, a01);
            a10 = mfma16(qa1, b0, a10); a11 = mfma16(qa1, b1, a11);
        }
        unsigned short* vb = VsT + (size_t)b * 131072;
        const int m0 = mt2 * 32 + quad * 4;
        f32x4 accs0[2] = {a00, a01};
        f32x4 accs1[2] = {a10, a11};
#pragma unroll
        for (int j = 0; j < 2; ++j) {
            const int c = nt * 32 + j * 16 + r16;
            const float bias = 16.f * bv[c];
#pragma unroll
            for (int r = 0; r < 4; ++r) {
                vb[(size_t)c * 256 + m0 + r]      = f2bf(accs0[j][r] + bias);
                vb[(size_t)c * 256 + m0 + 16 + r] = f2bf(accs1[j][r] + bias);
            }
        }
    }
}

// ---------------------------------------------------------------------------
// K3+K4 merged: scores + softmax + AV + expand, wave-coalesced writes.
// (unchanged from the 172.5 us verified pipeline)
// ---------------------------------------------------------------------------
__global__ void __launch_bounds__(256, 2)
score_av(const unsigned short* __restrict__ QK,
         const unsigned short* __restrict__ VsT,
         float* __restrict__ out)
{
    __shared__ union {
        float S[16][257];
        float osT[256][17];
    } u;
    __shared__ __align__(16) unsigned short Abf[16][264];   // +8 pad: row stride 528 B

    const int b = blockIdx.y;
    const int strip = blockIdx.x >> 1;      // 0..15
    const int chalf = blockIdx.x & 1;       // 0..1: which 256-channel half
    const int w = threadIdx.x >> 6, lane = threadIdx.x & 63;
    const int quad = lane >> 4, r16 = lane & 15;

    // ---- Phase 1: scores ----
    {
        const unsigned short* qp = QK + (size_t)(b * 256 + strip * 16 + r16) * 1024 + quad * 8;
        const unsigned short* kp0 = QK + (size_t)(b * 256 + w * 64 + r16) * 1024 + 512 + quad * 8;
        const unsigned short* kp1 = kp0 + 16 * 1024;
        const unsigned short* kp2 = kp0 + 32 * 1024;
        const unsigned short* kp3 = kp0 + 48 * 1024;

        f32x4 a0 = {0,0,0,0}, a1 = a0, a2 = a0, a3 = a0;
#pragma unroll 4
        for (int k = 0; k < 512; k += 32) {
            short8 qa = *(const short8*)(qp + k);
            short8 b0 = *(const short8*)(kp0 + k);
            short8 b1 = *(const short8*)(kp1 + k);
            short8 b2 = *(const short8*)(kp2 + k);
            short8 b3 = *(const short8*)(kp3 + k);
            a0 = mfma16(qa, b0, a0); a1 = mfma16(qa, b1, a1);
            a2 = mfma16(qa, b2, a2); a3 = mfma16(qa, b3, a3);
        }
        f32x4 accs[4] = {a0, a1, a2, a3};
#pragma unroll
        for (int j = 0; j < 4; ++j) {
            const int col = w * 64 + j * 16 + r16;
#pragma unroll
            for (int r = 0; r < 4; ++r)
                u.S[quad * 4 + r][col] = accs[j][r];
        }
    }
    __syncthreads();

    // ---- Phase 2: softmax -> bf16 A in LDS ----
    {
        const int t = threadIdx.x;
        const int r = t >> 4, idx = t & 15;     // row r, cols idx*16..+15
        float v[16];
        float mx = -3.4e38f;
#pragma unroll
        for (int j = 0; j < 16; ++j) {
            v[j] = u.S[r][idx * 16 + j] * 0.044194173824159216f;
            mx = fmaxf(mx, v[j]);
        }
        mx = fmaxf(mx, __shfl_xor(mx, 1));
        mx = fmaxf(mx, __shfl_xor(mx, 2));
        mx = fmaxf(mx, __shfl_xor(mx, 4));
        mx = fmaxf(mx, __shfl_xor(mx, 8));
        float sum = 0.f;
#pragma unroll
        for (int j = 0; j < 16; ++j) { v[j] = __expf(v[j] - mx); sum += v[j]; }
        sum += __shfl_xor(sum, 1);
        sum += __shfl_xor(sum, 2);
        sum += __shfl_xor(sum, 4);
        sum += __shfl_xor(sum, 8);
        const float inv = 1.f / sum;
        unsigned short* ap = &Abf[r][idx * 16];
#pragma unroll
        for (int j = 0; j < 16; j += 4)
            *(ushort4*)(ap + j) = make_ushort4(f2bf(v[j] * inv), f2bf(v[j + 1] * inv),
                                               f2bf(v[j + 2] * inv), f2bf(v[j + 3] * inv));
    }
    __syncthreads();

    // ---- Phase 3: AV for this c-half (per wave: 4 tiles of 16c x 16n) ----
    {
        f32x4 acc0 = {0,0,0,0}, acc1 = acc0, acc2 = acc0, acc3 = acc0;
        const unsigned short* vbase = VsT + (size_t)b * 131072 +
                                      (size_t)(chalf * 256 + w * 64 + r16) * 256 + quad * 8;
        const unsigned short* vp0 = vbase;
        const unsigned short* vp1 = vbase + 16 * 256;
        const unsigned short* vp2 = vbase + 32 * 256;
        const unsigned short* vp3 = vbase + 48 * 256;
#pragma unroll
        for (int kk = 0; kk < 256; kk += 32) {
            short8 a = *(const short8*)(&Abf[r16][kk + quad * 8]);
            short8 b0 = *(const short8*)(vp0 + kk);
            short8 b1 = *(const short8*)(vp1 + kk);
            short8 b2 = *(const short8*)(vp2 + kk);
            short8 b3 = *(const short8*)(vp3 + kk);
            acc0 = mfma16(a, b0, acc0); acc1 = mfma16(a, b1, acc1);
            acc2 = mfma16(a, b2, acc2); acc3 = mfma16(a, b3, acc3);
        }
        __syncthreads();                    // S dead; osT aliases it
        f32x4 accs[4] = {acc0, acc1, acc2, acc3};
#pragma unroll
        for (int i = 0; i < 4; ++i) {
            const int cl = w * 64 + i * 16 + r16;
#pragma unroll
            for (int r = 0; r < 4; ++r)
                u.osT[cl][quad * 4 + r] = accs[i][r];
        }
    }
    __syncthreads();

    // ---- Phase 4: expanded write, 1 KB contiguous per WAVE instruction ----
    {
        const int j = threadIdx.x & 63;     // float4 index within segment
        float* obase = out + (size_t)(b * 512 + chalf * 256) * 4096 + strip * 256 + j * 4;
#pragma unroll
        for (int it = 0; it < 64; ++it) {
            const int ch = it * 4 + w;
            const float v = u.osT[ch][j >> 2];
            *(float4*)(obase + (size_t)ch * 4096) = make_float4(v, v, v, v);
        }
    }
}

extern "C" void kernel_launch(void* const* d_in, const int* in_sizes, int n_in,
                              void* d_out, int out_size, void* d_ws, size_t ws_size,
                              hipStream_t stream) {
    const float* x  = (const float*)d_in[0];
    const float* Wq = (const float*)d_in[1];
    const float* bq = (const float*)d_in[2];
    const float* Wk = (const float*)d_in[3];
    const float* bk = (const float*)d_in[4];
    const float* Wv = (const float*)d_in[5];
    const float* bv = (const float*)d_in[6];
    float* out = (float*)d_out;

    // All scratch in d_ws; fully written before read each call.
    unsigned short* Wb   = (unsigned short*)d_ws;    // 786432 shorts (Wq|Wk|Wv)
    unsigned short* xavg = Wb + 786432;              // 1048576
    unsigned short* xsum = xavg + 1048576;           // 1048576
    unsigned short* QK   = xsum + 1048576;           // 2097152 (2048x1024)
    unsigned short* VsT  = QK + 2097152;             // 1048576 (8 x 512x256)

    // K1: coalesced-write plane reductions (512) + weight convert (384)
    prep_kernel<<<896, 256, 0, stream>>>(x, Wq, Wk, Wv, xavg, xsum, Wb);
    // K2: QK = xavg @ [Wq;Wk]^T + bias  AND  VsT = (xsum @ Wv^T + 16*bv)^T
    proj_gemm<<<768, 256, 0, stream>>>(xavg, xsum, Wb, bq, bk, bv, QK, VsT);
    // K3+K4 merged: scores + softmax + AV + expanded write (256 blocks)
    score_av<<<dim3(32, 8), 256, 0, stream>>>(QK, VsT, out);
}